// Round 1
// baseline (9928.640 us; speedup 1.0000x reference)
//
#include <hip/hip_runtime.h>

typedef __attribute__((ext_vector_type(8))) short s16x8;
typedef __attribute__((ext_vector_type(4))) float fx4;

static __device__ __forceinline__ unsigned short f2bf(float f){
  unsigned u = __float_as_uint(f);
  return (unsigned short)((u + 0x7fffu + ((u>>16)&1u)) >> 16);   // RNE
}
static __device__ __forceinline__ float bf2f(unsigned short s){
  return __uint_as_float(((unsigned)s)<<16);
}

// ---------------------------------------------------------------- W_out -> bf16
__global__ void k_cvt_wout(const float* __restrict__ w, unsigned short* __restrict__ o){
  int g = blockIdx.x*256 + threadIdx.x;
  int idx = g*4;                       // 524288 total, grid covers exactly
  float4 f = *(const float4*)(w + idx);
  unsigned u0 = (unsigned)f2bf(f.x) | ((unsigned)f2bf(f.y)<<16);
  unsigned u1 = (unsigned)f2bf(f.z) | ((unsigned)f2bf(f.w)<<16);
  *(uint2*)(o + idx) = make_uint2(u0, u1);
}

// ---------------------------------------------------------------- GEMM1: xp = x@W_ih^T + (b_ih+b_hh)
// A = x f32 [65536,512], B^T = W_ih f32 [1024,512], out xp bf16 laid out [T][B][H]
__global__ __launch_bounds__(256) void k_gemm_xp(
    const float* __restrict__ X, const float* __restrict__ Wih,
    const float* __restrict__ bih, const float* __restrict__ bhh,
    unsigned short* __restrict__ XP){
  __shared__ unsigned short As[128][40];
  __shared__ unsigned short Bs[128][40];
  const int bm = blockIdx.x, bn = blockIdx.y;
  const int tid = threadIdx.x, w = tid>>6, l = tid&63;
  const int wm = w>>1, wn = w&1;
  const int m0 = bm*128, n0 = bn*128;
  fx4 acc[4][4] = {};
  for (int kb = 0; kb < 512; kb += 32){
    #pragma unroll
    for (int q=0;q<4;q++){
      int f = tid + q*256;
      int row = f>>3, c4 = (f&7)*4;
      float4 v = *(const float4*)(X + (m0+row)*512 + kb + c4);
      unsigned u0 = (unsigned)f2bf(v.x) | ((unsigned)f2bf(v.y)<<16);
      unsigned u1 = (unsigned)f2bf(v.z) | ((unsigned)f2bf(v.w)<<16);
      *(uint2*)&As[row][c4] = make_uint2(u0,u1);
    }
    #pragma unroll
    for (int q=0;q<4;q++){
      int f = tid + q*256;
      int row = f>>3, c4 = (f&7)*4;
      float4 v = *(const float4*)(Wih + (n0+row)*512 + kb + c4);
      unsigned u0 = (unsigned)f2bf(v.x) | ((unsigned)f2bf(v.y)<<16);
      unsigned u1 = (unsigned)f2bf(v.z) | ((unsigned)f2bf(v.w)<<16);
      *(uint2*)&Bs[row][c4] = make_uint2(u0,u1);
    }
    __syncthreads();
    const int kbase = (l>>4)*8;
    s16x8 a[4], b[4];
    #pragma unroll
    for (int mt=0;mt<4;mt++) a[mt] = *(const s16x8*)&As[wm*64 + mt*16 + (l&15)][kbase];
    #pragma unroll
    for (int nt=0;nt<4;nt++) b[nt] = *(const s16x8*)&Bs[wn*64 + nt*16 + (l&15)][kbase];
    #pragma unroll
    for (int mt=0;mt<4;mt++)
      #pragma unroll
      for (int nt=0;nt<4;nt++)
        acc[mt][nt] = __builtin_amdgcn_mfma_f32_16x16x32_bf16(a[mt], b[nt], acc[mt][nt], 0,0,0);
    __syncthreads();
  }
  #pragma unroll
  for (int nt=0;nt<4;nt++){
    int n = n0 + wn*64 + nt*16 + (l&15);
    float bias = bih[n] + bhh[n];
    #pragma unroll
    for (int mt=0;mt<4;mt++){
      #pragma unroll
      for (int r=0;r<4;r++){
        int grow = m0 + wm*64 + mt*16 + (l>>4)*4 + r;   // = b*1024 + t
        int bb = grow >> 10, t = grow & 1023;
        XP[(t*64 + bb)*1024 + n] = f2bf(acc[mt][nt][r] + bias);
      }
    }
  }
}

// ---------------------------------------------------------------- recurrence
// 256 WGs = 16 batch-groups x 16 col-groups; W_hh slice register-resident.
// 16-WG group barrier via monotonic counter (release add / acquire spin, agent scope).
__global__ __launch_bounds__(256) void k_rnn(
    const float* __restrict__ Whh, const unsigned short* __restrict__ XP,
    unsigned short* __restrict__ HS, unsigned* __restrict__ cnt){
  __shared__ unsigned short hlds[4][1032];          // pad 8 -> conflict-free a-frag reads
  const int wg = blockIdx.x;
  const int gi = wg >> 4, gj = wg & 15;
  const int bi = gi*4, cj = gj*64;
  const int tid = threadIdx.x, w = tid>>6, l = tid&63;
  const int col = cj + w*16 + (l&15);
  const int kbase = (l>>4)*8;
  unsigned* myc = cnt + gi*32;                      // 128B-separated counters

  // load W_hh slice as resident MFMA B-fragments (bf16), 128 VGPRs/lane
  s16x8 wf[32];
  #pragma unroll
  for (int kk=0; kk<32; kk++){
    const float* p = Whh + col*1024 + kk*32 + kbase;
    float4 v0 = *(const float4*)p;
    float4 v1 = *(const float4*)(p+4);
    s16x8 s;
    s[0]=(short)f2bf(v0.x); s[1]=(short)f2bf(v0.y); s[2]=(short)f2bf(v0.z); s[3]=(short)f2bf(v0.w);
    s[4]=(short)f2bf(v1.x); s[5]=(short)f2bf(v1.y); s[6]=(short)f2bf(v1.z); s[7]=(short)f2bf(v1.w);
    wf[kk]=s;
  }

  // step 0: h0 = 0 -> h = tanh(xp_0)
  {
    int b = bi + (tid>>6);
    int c = cj + (tid&63);
    float xv = bf2f(XP[b*1024 + c]);                // t=0
    HS[(b*1024 + 0)*1024 + c] = f2bf(tanhf(xv));
  }
  __syncthreads();
  if (tid==0) __hip_atomic_fetch_add(myc, 1u, __ATOMIC_RELEASE, __HIP_MEMORY_SCOPE_AGENT);

  for (int s=1; s<1024; ++s){
    if (tid==0){
      unsigned target = 16u*(unsigned)s;
      while (__hip_atomic_load(myc, __ATOMIC_ACQUIRE, __HIP_MEMORY_SCOPE_AGENT) < target) { }
    }
    __syncthreads();
    // stage h_{s-1} slice (4 rows x 1024 bf16 = 8KB)
    {
      int r = tid>>6, c16 = (tid&63)*16;
      const unsigned short* src = HS + ((bi+r)*1024 + (s-1))*1024 + c16;
      uint4 v0 = *(const uint4*)src;
      uint4 v1 = *(const uint4*)(src+8);
      *(uint4*)&hlds[r][c16]   = v0;
      *(uint4*)&hlds[r][c16+8] = v1;
    }
    __syncthreads();
    fx4 acc = {0.f,0.f,0.f,0.f};
    const int arow = (l&15)&3;
    #pragma unroll
    for (int kk=0;kk<32;kk++){
      s16x8 af = *(const s16x8*)&hlds[arow][kk*32 + kbase];
      acc = __builtin_amdgcn_mfma_f32_16x16x32_bf16(af, wf[kk], acc, 0,0,0);
    }
    if (l < 16){
      #pragma unroll
      for (int r=0;r<4;r++){
        int b = bi + r;
        int c = cj + w*16 + l;
        float xv = bf2f(XP[(s*64 + b)*1024 + c]);
        float h = tanhf(acc[r] + xv);
        HS[(b*1024 + s)*1024 + c] = f2bf(h);
      }
    }
    __syncthreads();
    if (tid==0) __hip_atomic_fetch_add(myc, 1u, __ATOMIC_RELEASE, __HIP_MEMORY_SCOPE_AGENT);
  }
}

// ---------------------------------------------------------------- GEMM2: out = hs@W_out^T + b_out
// A = hs bf16 (lives in d_out), BN=512 full-row blocks -> safe in-place overwrite.
__global__ __launch_bounds__(512) void k_gemm_out(
    const unsigned short* __restrict__ HS, const unsigned short* __restrict__ WoutB,
    const float* __restrict__ bout, float* __restrict__ OUT){
  __shared__ unsigned short As[128][40];
  __shared__ unsigned short Bs[512][40];
  const int m0 = blockIdx.x*128;
  const int tid = threadIdx.x, w = tid>>6, l = tid&63;
  const int wm = w>>2, wn = w&3;                   // 2 x 4 waves: 64 rows x 128 cols each
  fx4 acc[4][8] = {};
  for (int kb = 0; kb < 1024; kb += 32){
    {
      int row = tid>>2, c8 = (tid&3)*8;
      *(uint4*)&As[row][c8] = *(const uint4*)(HS + (m0+row)*1024 + kb + c8);
    }
    #pragma unroll
    for (int q=0;q<4;q++){
      int f = tid + q*512;
      int row = f>>2, c8 = (f&3)*8;
      *(uint4*)&Bs[row][c8] = *(const uint4*)(WoutB + row*1024 + kb + c8);
    }
    __syncthreads();
    const int kbase = (l>>4)*8;
    s16x8 a[4], b[8];
    #pragma unroll
    for (int mt=0;mt<4;mt++) a[mt] = *(const s16x8*)&As[wm*64 + mt*16 + (l&15)][kbase];
    #pragma unroll
    for (int nt=0;nt<8;nt++) b[nt] = *(const s16x8*)&Bs[wn*128 + nt*16 + (l&15)][kbase];
    #pragma unroll
    for (int mt=0;mt<4;mt++)
      #pragma unroll
      for (int nt=0;nt<8;nt++)
        acc[mt][nt] = __builtin_amdgcn_mfma_f32_16x16x32_bf16(a[mt], b[nt], acc[mt][nt], 0,0,0);
    __syncthreads();
  }
  #pragma unroll
  for (int nt=0;nt<8;nt++){
    int n = wn*128 + nt*16 + (l&15);
    float bias = bout[n];
    #pragma unroll
    for (int mt=0;mt<4;mt++){
      #pragma unroll
      for (int r=0;r<4;r++){
        int row = m0 + wm*64 + mt*16 + (l>>4)*4 + r;
        OUT[row*512 + n] = acc[mt][nt][r] + bias;
      }
    }
  }
}

// ---------------------------------------------------------------- launch
extern "C" void kernel_launch(void* const* d_in, const int* in_sizes, int n_in,
                              void* d_out, int out_size, void* d_ws, size_t ws_size,
                              hipStream_t stream){
  const float* x    = (const float*)d_in[0];
  const float* Wih  = (const float*)d_in[1];
  const float* Whh  = (const float*)d_in[2];
  const float* bih  = (const float*)d_in[3];
  const float* bhh  = (const float*)d_in[4];
  const float* Wout = (const float*)d_in[5];
  const float* bout = (const float*)d_in[6];

  const size_t XP_BYTES = 134217728ull;            // 64*1024*1024*2 (bf16 [T][B][H])
  unsigned short* XP    = (unsigned short*)d_ws;
  unsigned short* WoutB = (unsigned short*)((char*)d_ws + XP_BYTES);
  unsigned*       cnt   = (unsigned*)((char*)d_ws + XP_BYTES + 1048576ull);
  unsigned short* HS    = (unsigned short*)d_out;  // hs bf16 scratch lives in d_out (exactly 128MB)
  float*          OUT   = (float*)d_out;

  hipMemsetAsync(cnt, 0, 2048, stream);
  k_cvt_wout<<<512, 256, 0, stream>>>(Wout, WoutB);
  dim3 g1(512, 8);
  k_gemm_xp<<<g1, 256, 0, stream>>>(x, Wih, bih, bhh, XP);
  k_rnn<<<256, 256, 0, stream>>>(Whh, XP, HS, cnt);
  k_gemm_out<<<512, 512, 0, stream>>>(HS, WoutB, bout, OUT);
}

// Round 3
// 5539.904 us; speedup vs baseline: 1.7922x; 1.7922x over previous
//
#include <hip/hip_runtime.h>

typedef __attribute__((ext_vector_type(8))) short s16x8;
typedef __attribute__((ext_vector_type(4))) float fx4;

static __device__ __forceinline__ unsigned short f2bf(float f){
  unsigned u = __float_as_uint(f);
  return (unsigned short)((u + 0x7fffu + ((u>>16)&1u)) >> 16);   // RNE
}
static __device__ __forceinline__ float bf2f(unsigned short s){
  return __uint_as_float(((unsigned)s)<<16);
}

// ---------------------------------------------------------------- W_out -> bf16
__global__ void k_cvt_wout(const float* __restrict__ w, unsigned short* __restrict__ o){
  int g = blockIdx.x*256 + threadIdx.x;
  int idx = g*4;                       // 524288 total, grid covers exactly
  float4 f = *(const float4*)(w + idx);
  unsigned u0 = (unsigned)f2bf(f.x) | ((unsigned)f2bf(f.y)<<16);
  unsigned u1 = (unsigned)f2bf(f.z) | ((unsigned)f2bf(f.w)<<16);
  *(uint2*)(o + idx) = make_uint2(u0, u1);
}

// ---------------------------------------------------------------- GEMM1: xp = x@W_ih^T + (b_ih+b_hh)
// A = x f32 [65536,512], B^T = W_ih f32 [1024,512], out xp bf16 laid out [T][B][H]
__global__ __launch_bounds__(256) void k_gemm_xp(
    const float* __restrict__ X, const float* __restrict__ Wih,
    const float* __restrict__ bih, const float* __restrict__ bhh,
    unsigned short* __restrict__ XP){
  __shared__ unsigned short As[128][40];
  __shared__ unsigned short Bs[128][40];
  const int bm = blockIdx.x, bn = blockIdx.y;
  const int tid = threadIdx.x, w = tid>>6, l = tid&63;
  const int wm = w>>1, wn = w&1;
  const int m0 = bm*128, n0 = bn*128;
  fx4 acc[4][4] = {};
  for (int kb = 0; kb < 512; kb += 32){
    #pragma unroll
    for (int q=0;q<4;q++){
      int f = tid + q*256;
      int row = f>>3, c4 = (f&7)*4;
      float4 v = *(const float4*)(X + (m0+row)*512 + kb + c4);
      unsigned u0 = (unsigned)f2bf(v.x) | ((unsigned)f2bf(v.y)<<16);
      unsigned u1 = (unsigned)f2bf(v.z) | ((unsigned)f2bf(v.w)<<16);
      *(uint2*)&As[row][c4] = make_uint2(u0,u1);
    }
    #pragma unroll
    for (int q=0;q<4;q++){
      int f = tid + q*256;
      int row = f>>3, c4 = (f&7)*4;
      float4 v = *(const float4*)(Wih + (n0+row)*512 + kb + c4);
      unsigned u0 = (unsigned)f2bf(v.x) | ((unsigned)f2bf(v.y)<<16);
      unsigned u1 = (unsigned)f2bf(v.z) | ((unsigned)f2bf(v.w)<<16);
      *(uint2*)&Bs[row][c4] = make_uint2(u0,u1);
    }
    __syncthreads();
    const int kbase = (l>>4)*8;
    s16x8 a[4], b[4];
    #pragma unroll
    for (int mt=0;mt<4;mt++) a[mt] = *(const s16x8*)&As[wm*64 + mt*16 + (l&15)][kbase];
    #pragma unroll
    for (int nt=0;nt<4;nt++) b[nt] = *(const s16x8*)&Bs[wn*64 + nt*16 + (l&15)][kbase];
    #pragma unroll
    for (int mt=0;mt<4;mt++)
      #pragma unroll
      for (int nt=0;nt<4;nt++)
        acc[mt][nt] = __builtin_amdgcn_mfma_f32_16x16x32_bf16(a[mt], b[nt], acc[mt][nt], 0,0,0);
    __syncthreads();
  }
  #pragma unroll
  for (int nt=0;nt<4;nt++){
    int n = n0 + wn*64 + nt*16 + (l&15);
    float bias = bih[n] + bhh[n];
    #pragma unroll
    for (int mt=0;mt<4;mt++){
      #pragma unroll
      for (int r=0;r<4;r++){
        int grow = m0 + wm*64 + mt*16 + (l>>4)*4 + r;   // = b*1024 + t
        int bb = grow >> 10, t = grow & 1023;
        XP[(t*64 + bb)*1024 + n] = f2bf(acc[mt][nt][r] + bias);
      }
    }
  }
}

// ---------------------------------------------------------------- recurrence
// 256 WGs = 16 batch-groups x 16 col-groups; W_hh slice register-resident.
// h transport: sc1 write-through relaxed atomic stores (LLC-coherent, L2
// never dirtied, never invalidated -> XP stays L2-resident).
// Ordering: the ONE hole R2 had is plugged here — the producer's counter
// bump is a RELEASE fetch_add, which emits buffer_wbl2 sc1 + s_waitcnt
// vmcnt(0) before the LLC atomic: the wbl2 drains in-flight write-through
// data to the coherence point, so counter-visible => h-visible.
// Consumer needs NO acquire/inv: each HS[.,s-1,.] line is a unique
// write-once/read-once address; no XCD L2 can hold a stale copy before the
// release (any thread past the spin reads post-release), and same-XCD
// consumers hit the producer's write-through-updated L2 line.
__global__ __launch_bounds__(256) void k_rnn(
    const float* __restrict__ Whh, const unsigned short* __restrict__ XP,
    unsigned short* __restrict__ HS, unsigned* __restrict__ cnt){
  __shared__ unsigned short hlds[4][1032];
  const int wg = blockIdx.x;
  const int gi = wg >> 4, gj = wg & 15;
  const int bi = gi*4, cj = gj*64;
  const int tid = threadIdx.x, w = tid>>6, l = tid&63;
  const int col = cj + w*16 + (l&15);
  const int kbase = (l>>4)*8;
  unsigned* myc = cnt + gi*32;                      // 128B-separated counters

  // load W_hh slice as resident MFMA B-fragments (bf16), 128 VGPRs/lane
  s16x8 wf[32];
  #pragma unroll
  for (int kk=0; kk<32; kk++){
    const float* p = Whh + col*1024 + kk*32 + kbase;
    float4 v0 = *(const float4*)p;
    float4 v1 = *(const float4*)(p+4);
    s16x8 s;
    s[0]=(short)f2bf(v0.x); s[1]=(short)f2bf(v0.y); s[2]=(short)f2bf(v0.z); s[3]=(short)f2bf(v0.w);
    s[4]=(short)f2bf(v1.x); s[5]=(short)f2bf(v1.y); s[6]=(short)f2bf(v1.z); s[7]=(short)f2bf(v1.w);
    wf[kk]=s;
  }

  // step 0: h0 = 0 -> h = tanh(xp_0)
  {
    int b = bi + (tid>>6);
    int c = cj + (tid&63);
    float xv = bf2f(XP[b*1024 + c]);                // t=0
    unsigned short hv = f2bf(tanhf(xv));
    __hip_atomic_store(&HS[(b*1024 + 0)*1024 + c], hv,
                       __ATOMIC_RELAXED, __HIP_MEMORY_SCOPE_AGENT);
  }
  __syncthreads();                                  // per-wave vmcnt drain
  if (tid==0) __hip_atomic_fetch_add(myc, 1u, __ATOMIC_RELEASE, __HIP_MEMORY_SCOPE_AGENT);

  const int xcol = cj + w*16 + l;                   // for l<16 epilogue path
  for (int s=1; s<1024; ++s){
    // prefetch this step's xp into regs (plain load, L2-warm) — hides under spin
    float xv[4];
    if (l < 16){
      #pragma unroll
      for (int r=0;r<4;r++)
        xv[r] = bf2f(XP[((s*64)+(bi+r))*1024 + xcol]);
    }
    if (tid==0){
      unsigned target = 16u*(unsigned)s;
      while (__hip_atomic_load(myc, __ATOMIC_RELAXED, __HIP_MEMORY_SCOPE_AGENT) < target) { }
    }
    __syncthreads();
    // stage h_{s-1} slice (4 rows x 2KB): plain coalesced 16B loads
    // (coherent per the release argument above; may hit same-XCD L2)
    {
      const unsigned short* rowp = HS + ((bi+w)*1024 + (s-1))*1024;
      uint4 v0 = *(const uint4*)(rowp + l*8);
      uint4 v1 = *(const uint4*)(rowp + 512 + l*8);
      *(uint4*)&hlds[w][l*8]       = v0;
      *(uint4*)&hlds[w][512 + l*8] = v1;
    }
    __syncthreads();
    // 4 independent accumulators -> dep chain 32 -> 8
    const int arow = (l&15)&3;
    fx4 ac0 = {0.f,0.f,0.f,0.f}, ac1 = ac0, ac2 = ac0, ac3 = ac0;
    #pragma unroll
    for (int kk=0;kk<32;kk+=4){
      s16x8 a0 = *(const s16x8*)&hlds[arow][(kk+0)*32 + kbase];
      s16x8 a1 = *(const s16x8*)&hlds[arow][(kk+1)*32 + kbase];
      s16x8 a2 = *(const s16x8*)&hlds[arow][(kk+2)*32 + kbase];
      s16x8 a3 = *(const s16x8*)&hlds[arow][(kk+3)*32 + kbase];
      ac0 = __builtin_amdgcn_mfma_f32_16x16x32_bf16(a0, wf[kk+0], ac0, 0,0,0);
      ac1 = __builtin_amdgcn_mfma_f32_16x16x32_bf16(a1, wf[kk+1], ac1, 0,0,0);
      ac2 = __builtin_amdgcn_mfma_f32_16x16x32_bf16(a2, wf[kk+2], ac2, 0,0,0);
      ac3 = __builtin_amdgcn_mfma_f32_16x16x32_bf16(a3, wf[kk+3], ac3, 0,0,0);
    }
    fx4 acc = (ac0+ac1)+(ac2+ac3);
    if (l < 16){
      #pragma unroll
      for (int r=0;r<4;r++){
        int b = bi + r;
        float h = tanhf(acc[r] + xv[r]);
        __hip_atomic_store(&HS[(b*1024 + s)*1024 + xcol], f2bf(h),
                           __ATOMIC_RELAXED, __HIP_MEMORY_SCOPE_AGENT);
      }
    }
    __syncthreads();                                // per-wave vmcnt drain
    if (tid==0) __hip_atomic_fetch_add(myc, 1u, __ATOMIC_RELEASE, __HIP_MEMORY_SCOPE_AGENT);
  }
}

// ---------------------------------------------------------------- GEMM2: out = hs@W_out^T + b_out
// A = hs bf16 (lives in d_out), BN=512 full-row blocks -> safe in-place overwrite.
__global__ __launch_bounds__(512) void k_gemm_out(
    const unsigned short* __restrict__ HS, const unsigned short* __restrict__ WoutB,
    const float* __restrict__ bout, float* __restrict__ OUT){
  __shared__ unsigned short As[128][40];
  __shared__ unsigned short Bs[512][40];
  const int m0 = blockIdx.x*128;
  const int tid = threadIdx.x, w = tid>>6, l = tid&63;
  const int wm = w>>2, wn = w&3;                   // 2 x 4 waves: 64 rows x 128 cols each
  fx4 acc[4][8] = {};
  for (int kb = 0; kb < 1024; kb += 32){
    {
      int row = tid>>2, c8 = (tid&3)*8;
      *(uint4*)&As[row][c8] = *(const uint4*)(HS + (m0+row)*1024 + kb + c8);
    }
    #pragma unroll
    for (int q=0;q<4;q++){
      int f = tid + q*512;
      int row = f>>2, c8 = (f&3)*8;
      *(uint4*)&Bs[row][c8] = *(const uint4*)(WoutB + row*1024 + kb + c8);
    }
    __syncthreads();
    const int kbase = (l>>4)*8;
    s16x8 a[4], b[8];
    #pragma unroll
    for (int mt=0;mt<4;mt++) a[mt] = *(const s16x8*)&As[wm*64 + mt*16 + (l&15)][kbase];
    #pragma unroll
    for (int nt=0;nt<8;nt++) b[nt] = *(const s16x8*)&Bs[wn*128 + nt*16 + (l&15)][kbase];
    #pragma unroll
    for (int mt=0;mt<4;mt++)
      #pragma unroll
      for (int nt=0;nt<8;nt++)
        acc[mt][nt] = __builtin_amdgcn_mfma_f32_16x16x32_bf16(a[mt], b[nt], acc[mt][nt], 0,0,0);
    __syncthreads();
  }
  #pragma unroll
  for (int nt=0;nt<8;nt++){
    int n = wn*128 + nt*16 + (l&15);
    float bias = bout[n];
    #pragma unroll
    for (int mt=0;mt<4;mt++){
      #pragma unroll
      for (int r=0;r<4;r++){
        int row = m0 + wm*64 + mt*16 + (l>>4)*4 + r;
        OUT[row*512 + n] = acc[mt][nt][r] + bias;
      }
    }
  }
}

// ---------------------------------------------------------------- launch
extern "C" void kernel_launch(void* const* d_in, const int* in_sizes, int n_in,
                              void* d_out, int out_size, void* d_ws, size_t ws_size,
                              hipStream_t stream){
  const float* x    = (const float*)d_in[0];
  const float* Wih  = (const float*)d_in[1];
  const float* Whh  = (const float*)d_in[2];
  const float* bih  = (const float*)d_in[3];
  const float* bhh  = (const float*)d_in[4];
  const float* Wout = (const float*)d_in[5];
  const float* bout = (const float*)d_in[6];

  const size_t XP_BYTES = 134217728ull;            // 64*1024*1024*2 (bf16 [T][B][H])
  unsigned short* XP    = (unsigned short*)d_ws;
  unsigned short* WoutB = (unsigned short*)((char*)d_ws + XP_BYTES);
  unsigned*       cnt   = (unsigned*)((char*)d_ws + XP_BYTES + 1048576ull);
  unsigned short* HS    = (unsigned short*)d_out;  // hs bf16 scratch lives in d_out (exactly 128MB)
  float*          OUT   = (float*)d_out;

  hipMemsetAsync(cnt, 0, 2048, stream);
  k_cvt_wout<<<512, 256, 0, stream>>>(Wout, WoutB);
  dim3 g1(512, 8);
  k_gemm_xp<<<g1, 256, 0, stream>>>(x, Wih, bih, bhh, XP);
  k_rnn<<<256, 256, 0, stream>>>(Whh, XP, HS, cnt);
  k_gemm_out<<<512, 512, 0, stream>>>(HS, WoutB, bout, OUT);
}

// Round 4
// 3049.499 us; speedup vs baseline: 3.2558x; 1.8167x over previous
//
#include <hip/hip_runtime.h>

typedef __attribute__((ext_vector_type(8))) short s16x8;
typedef __attribute__((ext_vector_type(4))) float fx4;

static __device__ __forceinline__ unsigned short f2bf(float f){
  unsigned u = __float_as_uint(f);
  return (unsigned short)((u + 0x7fffu + ((u>>16)&1u)) >> 16);   // RNE
}
static __device__ __forceinline__ float bf2f(unsigned short s){
  return __uint_as_float(((unsigned)s)<<16);
}

// ---------------------------------------------------------------- W_out -> bf16
__global__ void k_cvt_wout(const float* __restrict__ w, unsigned short* __restrict__ o){
  int g = blockIdx.x*256 + threadIdx.x;
  int idx = g*4;
  float4 f = *(const float4*)(w + idx);
  unsigned u0 = (unsigned)f2bf(f.x) | ((unsigned)f2bf(f.y)<<16);
  unsigned u1 = (unsigned)f2bf(f.z) | ((unsigned)f2bf(f.w)<<16);
  *(uint2*)(o + idx) = make_uint2(u0, u1);
}

// ---------------------------------------------------------------- GEMM1: xp = x@W_ih^T + (b_ih+b_hh)
__global__ __launch_bounds__(256) void k_gemm_xp(
    const float* __restrict__ X, const float* __restrict__ Wih,
    const float* __restrict__ bih, const float* __restrict__ bhh,
    unsigned short* __restrict__ XP){
  __shared__ unsigned short As[128][40];
  __shared__ unsigned short Bs[128][40];
  const int bm = blockIdx.x, bn = blockIdx.y;
  const int tid = threadIdx.x, w = tid>>6, l = tid&63;
  const int wm = w>>1, wn = w&1;
  const int m0 = bm*128, n0 = bn*128;
  fx4 acc[4][4] = {};
  for (int kb = 0; kb < 512; kb += 32){
    #pragma unroll
    for (int q=0;q<4;q++){
      int f = tid + q*256;
      int row = f>>3, c4 = (f&7)*4;
      float4 v = *(const float4*)(X + (m0+row)*512 + kb + c4);
      unsigned u0 = (unsigned)f2bf(v.x) | ((unsigned)f2bf(v.y)<<16);
      unsigned u1 = (unsigned)f2bf(v.z) | ((unsigned)f2bf(v.w)<<16);
      *(uint2*)&As[row][c4] = make_uint2(u0,u1);
    }
    #pragma unroll
    for (int q=0;q<4;q++){
      int f = tid + q*256;
      int row = f>>3, c4 = (f&7)*4;
      float4 v = *(const float4*)(Wih + (n0+row)*512 + kb + c4);
      unsigned u0 = (unsigned)f2bf(v.x) | ((unsigned)f2bf(v.y)<<16);
      unsigned u1 = (unsigned)f2bf(v.z) | ((unsigned)f2bf(v.w)<<16);
      *(uint2*)&Bs[row][c4] = make_uint2(u0,u1);
    }
    __syncthreads();
    const int kbase = (l>>4)*8;
    s16x8 a[4], b[4];
    #pragma unroll
    for (int mt=0;mt<4;mt++) a[mt] = *(const s16x8*)&As[wm*64 + mt*16 + (l&15)][kbase];
    #pragma unroll
    for (int nt=0;nt<4;nt++) b[nt] = *(const s16x8*)&Bs[wn*64 + nt*16 + (l&15)][kbase];
    #pragma unroll
    for (int mt=0;mt<4;mt++)
      #pragma unroll
      for (int nt=0;nt<4;nt++)
        acc[mt][nt] = __builtin_amdgcn_mfma_f32_16x16x32_bf16(a[mt], b[nt], acc[mt][nt], 0,0,0);
    __syncthreads();
  }
  #pragma unroll
  for (int nt=0;nt<4;nt++){
    int n = n0 + wn*64 + nt*16 + (l&15);
    float bias = bih[n] + bhh[n];
    #pragma unroll
    for (int mt=0;mt<4;mt++){
      #pragma unroll
      for (int r=0;r<4;r++){
        int grow = m0 + wm*64 + mt*16 + (l>>4)*4 + r;   // = b*1024 + t
        int bb = grow >> 10, t = grow & 1023;
        XP[(t*64 + bb)*1024 + n] = f2bf(acc[mt][nt][r] + bias);
      }
    }
  }
}

// ---------------------------------------------------------------- recurrence
// 128 WGs = 8 batch-groups (8 rows) x 16 col-groups (64 cols). Under the
// measured round-robin dispatch, group gi = {wg : wg%8==gi} lands entirely on
// XCD gi. A registration phase publishes each WG's HW_REG_XCC_ID and every
// group VERIFIES purity at runtime (correctness never assumes placement):
//   pure  -> LOCAL protocol: h via plain write-through stores into the shared
//            XCD L2 (fresh addresses each step -> no stale L1/L2 copies),
//            per-wave s_waitcnt vmcnt(0) + barrier, then lane-0 sc1 FLAG STORE
//            (no RMW, no buffer_wbl2 — h never needs to leave the XCD; flag at
//            LLC orders after h-in-L2 because it issues post-drain).
//            Consumers: 16-lane parallel sc1 flag poll + __all, plain L2 loads.
//   mixed -> R3-proven fallback: sc1 atomic h stores + RELEASE fetch_add
//            (buffer_wbl2 drain) + counter spin.
__global__ __launch_bounds__(256) void k_rnn(
    const float* __restrict__ Whh, const unsigned short* __restrict__ XP,
    unsigned short* __restrict__ HS, unsigned* __restrict__ ctrl){
  __shared__ unsigned short hlds[8][1032];
  const int wg = blockIdx.x;
  const int gi = wg & 7;            // batch-group (XCD under round-robin)
  const int gj = wg >> 3;           // rank within group / col-group
  const int bi = gi*8, cj = gj*64;
  const int tid = threadIdx.x, w = tid>>6, l = tid&63;
  const int kbase = (l>>4)*8;
  unsigned* flags = ctrl + 256;                 // flag(gi,rank) at [(gi*16+rank)*16]
  unsigned* fc    = ctrl + 4096 + gi*32;        // fallback counter

  // --- registration: publish XCD id, barrier, verify group purity ---
  unsigned xcd;
  asm volatile("s_getreg_b32 %0, hwreg(HW_REG_XCC_ID)" : "=s"(xcd));
  xcd = (xcd & 0xffu) | 0x100u;                 // tag so 0 != "unwritten"
  if (tid==0){
    __hip_atomic_store(&ctrl[16+wg], xcd, __ATOMIC_RELAXED, __HIP_MEMORY_SCOPE_AGENT);
    __hip_atomic_fetch_add(&ctrl[0], 1u, __ATOMIC_RELEASE, __HIP_MEMORY_SCOPE_AGENT);
    while (__hip_atomic_load(&ctrl[0], __ATOMIC_RELAXED, __HIP_MEMORY_SCOPE_AGENT) < 128u){}
  }
  __syncthreads();
  bool ok = true;
  if (l < 16){
    unsigned peer = __hip_atomic_load(&ctrl[16 + l*8 + gi], __ATOMIC_RELAXED, __HIP_MEMORY_SCOPE_AGENT);
    ok = (peer == xcd);
  }
  const bool local = __all(ok);

  // --- W_hh slice as resident MFMA B-fragments (128 VGPR/lane) ---
  const int col = cj + w*16 + (l&15);
  s16x8 wf[32];
  #pragma unroll
  for (int kk=0; kk<32; kk++){
    const float* p = Whh + col*1024 + kk*32 + kbase;
    float4 v0 = *(const float4*)p;
    float4 v1 = *(const float4*)(p+4);
    s16x8 s;
    s[0]=(short)f2bf(v0.x); s[1]=(short)f2bf(v0.y); s[2]=(short)f2bf(v0.z); s[3]=(short)f2bf(v0.w);
    s[4]=(short)f2bf(v1.x); s[5]=(short)f2bf(v1.y); s[6]=(short)f2bf(v1.z); s[7]=(short)f2bf(v1.w);
    wf[kk]=s;
  }

  const int ecol = cj + w*16 + (l&15);
  // --- step 0: h = tanh(xp_0) ---
  if (l < 32){
    #pragma unroll
    for (int r=0;r<4;r++){
      int row = (l>>4)*4 + r;                   // 0..7
      float xv = bf2f(XP[(bi+row)*1024 + ecol]);
      unsigned short hv = f2bf(tanhf(xv));
      if (local) HS[((bi+row)*1024 + 0)*1024 + ecol] = hv;
      else __hip_atomic_store(&HS[((bi+row)*1024+0)*1024+ecol], hv,
                              __ATOMIC_RELAXED, __HIP_MEMORY_SCOPE_AGENT);
    }
  }
  asm volatile("s_waitcnt vmcnt(0)" ::: "memory");
  __syncthreads();
  if (tid==0){
    if (local) __hip_atomic_store(&flags[(gi*16+gj)*16], 1u, __ATOMIC_RELAXED, __HIP_MEMORY_SCOPE_AGENT);
    else __hip_atomic_fetch_add(fc, 1u, __ATOMIC_RELEASE, __HIP_MEMORY_SCOPE_AGENT);
  }

  for (int s=1; s<1024; ++s){
    // xp prefetch (overlaps the spin)
    float xv[4];
    if (l < 32){
      #pragma unroll
      for (int r=0;r<4;r++)
        xv[r] = bf2f(XP[(s*64 + bi + (l>>4)*4 + r)*1024 + ecol]);
    }
    // wait for h_{s-1}
    if (local){
      if (tid < 16){
        for(;;){
          unsigned v = __hip_atomic_load(&flags[(gi*16+tid)*16], __ATOMIC_RELAXED, __HIP_MEMORY_SCOPE_AGENT);
          if (__all(v >= (unsigned)s)) break;
        }
      }
    } else {
      if (tid==0){
        while (__hip_atomic_load(fc, __ATOMIC_RELAXED, __HIP_MEMORY_SCOPE_AGENT) < 16u*(unsigned)s){}
      }
    }
    __syncthreads();
    // stage h_{s-1}: 8 rows x 2KB, plain coalesced 16B loads (L2-local when pure)
    {
      int r0 = w*2 + (l>>5);
      int c0 = (l&31)*8;
      const unsigned short* rowp = HS + ((bi + r0)*1024 + (s-1))*1024;
      #pragma unroll
      for (int j=0;j<4;j++)
        *(uint4*)&hlds[r0][c0 + j*256] = *(const uint4*)(rowp + c0 + j*256);
    }
    __syncthreads();
    // 32 MFMA, 4 independent chains
    const int arow = (l&15)&7;
    fx4 ac0 = {0.f,0.f,0.f,0.f}, ac1 = ac0, ac2 = ac0, ac3 = ac0;
    #pragma unroll
    for (int kk=0;kk<32;kk+=4){
      s16x8 a0 = *(const s16x8*)&hlds[arow][(kk+0)*32 + kbase];
      s16x8 a1 = *(const s16x8*)&hlds[arow][(kk+1)*32 + kbase];
      s16x8 a2 = *(const s16x8*)&hlds[arow][(kk+2)*32 + kbase];
      s16x8 a3 = *(const s16x8*)&hlds[arow][(kk+3)*32 + kbase];
      ac0 = __builtin_amdgcn_mfma_f32_16x16x32_bf16(a0, wf[kk+0], ac0, 0,0,0);
      ac1 = __builtin_amdgcn_mfma_f32_16x16x32_bf16(a1, wf[kk+1], ac1, 0,0,0);
      ac2 = __builtin_amdgcn_mfma_f32_16x16x32_bf16(a2, wf[kk+2], ac2, 0,0,0);
      ac3 = __builtin_amdgcn_mfma_f32_16x16x32_bf16(a3, wf[kk+3], ac3, 0,0,0);
    }
    fx4 acc = (ac0+ac1)+(ac2+ac3);
    if (l < 32){
      #pragma unroll
      for (int r=0;r<4;r++){
        int row = (l>>4)*4 + r;
        float h = tanhf(acc[r] + xv[r]);
        unsigned short hv = f2bf(h);
        if (local) HS[((bi+row)*1024 + s)*1024 + ecol] = hv;
        else __hip_atomic_store(&HS[((bi+row)*1024+s)*1024+ecol], hv,
                                __ATOMIC_RELAXED, __HIP_MEMORY_SCOPE_AGENT);
      }
    }
    asm volatile("s_waitcnt vmcnt(0)" ::: "memory");
    __syncthreads();
    if (tid==0){
      if (local) __hip_atomic_store(&flags[(gi*16+gj)*16], (unsigned)(s+1), __ATOMIC_RELAXED, __HIP_MEMORY_SCOPE_AGENT);
      else __hip_atomic_fetch_add(fc, 1u, __ATOMIC_RELEASE, __HIP_MEMORY_SCOPE_AGENT);
    }
  }
}

// ---------------------------------------------------------------- GEMM2: out = hs@W_out^T + b_out
__global__ __launch_bounds__(512) void k_gemm_out(
    const unsigned short* __restrict__ HS, const unsigned short* __restrict__ WoutB,
    const float* __restrict__ bout, float* __restrict__ OUT){
  __shared__ unsigned short As[128][40];
  __shared__ unsigned short Bs[512][40];
  const int m0 = blockIdx.x*128;
  const int tid = threadIdx.x, w = tid>>6, l = tid&63;
  const int wm = w>>2, wn = w&3;
  fx4 acc[4][8] = {};
  for (int kb = 0; kb < 1024; kb += 32){
    {
      int row = tid>>2, c8 = (tid&3)*8;
      *(uint4*)&As[row][c8] = *(const uint4*)(HS + (m0+row)*1024 + kb + c8);
    }
    #pragma unroll
    for (int q=0;q<4;q++){
      int f = tid + q*512;
      int row = f>>2, c8 = (f&3)*8;
      *(uint4*)&Bs[row][c8] = *(const uint4*)(WoutB + row*1024 + kb + c8);
    }
    __syncthreads();
    const int kbase = (l>>4)*8;
    s16x8 a[4], b[8];
    #pragma unroll
    for (int mt=0;mt<4;mt++) a[mt] = *(const s16x8*)&As[wm*64 + mt*16 + (l&15)][kbase];
    #pragma unroll
    for (int nt=0;nt<8;nt++) b[nt] = *(const s16x8*)&Bs[wn*128 + nt*16 + (l&15)][kbase];
    #pragma unroll
    for (int mt=0;mt<4;mt++)
      #pragma unroll
      for (int nt=0;nt<8;nt++)
        acc[mt][nt] = __builtin_amdgcn_mfma_f32_16x16x32_bf16(a[mt], b[nt], acc[mt][nt], 0,0,0);
    __syncthreads();
  }
  #pragma unroll
  for (int nt=0;nt<8;nt++){
    int n = wn*128 + nt*16 + (l&15);
    float bias = bout[n];
    #pragma unroll
    for (int mt=0;mt<4;mt++){
      #pragma unroll
      for (int r=0;r<4;r++){
        int row = m0 + wm*64 + mt*16 + (l>>4)*4 + r;
        OUT[row*512 + n] = acc[mt][nt][r] + bias;
      }
    }
  }
}

// ---------------------------------------------------------------- launch
extern "C" void kernel_launch(void* const* d_in, const int* in_sizes, int n_in,
                              void* d_out, int out_size, void* d_ws, size_t ws_size,
                              hipStream_t stream){
  const float* x    = (const float*)d_in[0];
  const float* Wih  = (const float*)d_in[1];
  const float* Whh  = (const float*)d_in[2];
  const float* bih  = (const float*)d_in[3];
  const float* bhh  = (const float*)d_in[4];
  const float* Wout = (const float*)d_in[5];
  const float* bout = (const float*)d_in[6];

  const size_t XP_BYTES = 134217728ull;            // bf16 xp, [T][B][H]
  unsigned short* XP    = (unsigned short*)d_ws;
  unsigned short* WoutB = (unsigned short*)((char*)d_ws + XP_BYTES);
  unsigned*       ctrl  = (unsigned*)((char*)d_ws + XP_BYTES + 1048576ull);
  unsigned short* HS    = (unsigned short*)d_out;  // hs bf16 lives in d_out
  float*          OUT   = (float*)d_out;

  hipMemsetAsync(ctrl, 0, 32768, stream);
  k_cvt_wout<<<512, 256, 0, stream>>>(Wout, WoutB);
  dim3 g1(512, 8);
  k_gemm_xp<<<g1, 256, 0, stream>>>(x, Wih, bih, bhh, XP);
  k_rnn<<<128, 256, 0, stream>>>(Whh, XP, HS, ctrl);
  k_gemm_out<<<512, 512, 0, stream>>>(HS, WoutB, bout, OUT);
}